// Round 4
// baseline (339.326 us; speedup 1.0000x reference)
//
#include <hip/hip_runtime.h>
#include <hip/hip_bf16.h>

// Problem constants (match reference file)
constexpr int K     = 8192;
constexpr int N4    = 6144;    // int4 rows
constexpr int N8    = 2048;    // uint8 rows
constexpr int NT    = N4 + N8; // 8192 output columns
constexpr int NG    = K / 128; // 64 groups per int4 row
constexpr int KS    = 4096;    // K ints per split (split-K x2)
constexpr int KT    = 256;     // K ints per K-step (16-row tile = 16 KB)
constexpr int NSTEP = KS / KT; // 16
constexpr int ROWB  = KT * 4 + 16; // 1040 B per LDS row (+16B pad: conflict-floor ds_read_b128)

typedef short  short8  __attribute__((ext_vector_type(8)));
typedef float  floatx4 __attribute__((ext_vector_type(4)));

__device__ inline short f2bf(float f) {
    __hip_bfloat16 h = __float2bfloat16(f);   // RNE
    return __builtin_bit_cast(short, h);
}

// global -> LDS direct copy, 16B per lane: LDS dest = base + lane*16 (linear),
// global src per-lane. Each call streams 1 KB CONTIGUOUS from one weight row —
// this is the whole point: round 0-3 read weights with 16 rows interleaved per
// instruction (32KB-apart lines, 20% DRAM efficiency); this restores sequential
// streams (fills hit 86% with the same shape of traffic).
__device__ inline void gload_lds16(const void* g, void* l) {
    __builtin_amdgcn_global_load_lds(
        (const __attribute__((address_space(1))) void*)g,
        (__attribute__((address_space(3))) void*)l, 16, 0, 0);
}

// ---------------------------------------------------------------------------
// Prep: x2bf = bf16(x/awq) stored in MFMA A-fragment order:
//   x2bf[c*512 + lane*8 + j] = X[m = lane&15][k = c*32 + (lane>>4)*8 + j]
// Also: fwd = inverse of inv_perm, and out pre-filled with bias.
// ---------------------------------------------------------------------------
__global__ void prep_kernel(const float* __restrict__ x,
                            const float* __restrict__ awq,
                            const int*   __restrict__ inv_perm,
                            const float* __restrict__ bias,
                            short* __restrict__ x2bf,
                            int*   __restrict__ fwd,
                            float* __restrict__ out) {
    const int tid  = blockIdx.x * blockDim.x + threadIdx.x;   // 0..131071
    const int c    = tid >> 9;
    const int rem  = tid & 511;
    const int lane = rem >> 3;
    const int j    = rem & 7;
    const int m    = lane & 15;
    const int k    = c * 32 + (lane >> 4) * 8 + j;
    x2bf[tid] = f2bf(x[m * K + k] / awq[k]);
    if (tid < NT) fwd[inv_perm[tid]] = tid;
    out[tid] = bias[tid & (NT - 1)];          // out = bias, pre-perm indexed
}

// ---------------------------------------------------------------------------
// Split-K x2 MFMA GEMV with LDS-staged, sequentially-read weights.
// Block = 4 waves = one 16-row tile x half of K (16 steps of 256 k).
// Per step: each wave stages 4 rows x 1KB contiguous via global_load_lds
// (double-buffered; counted vmcnt(4) + raw s_barrier keeps the next tile's
// loads in flight ACROSS the barrier — __syncthreads would drain them).
// Wave w computes chunks {2w, 2w+1} of each step from LDS (ds_read_b128,
// +16B row pad -> bank-conflict floor), dequants, MFMAs.
//   int4 rows : wf = w*s - 8s ; uint8 rows: wf = w - 128 (exact in bf16,
//   s8 + 8*s*sum_x correction folded algebraically, applied in epilogue)
// Grid 1024 blocks = 4 blocks/CU (LDS 33.3KB). Epilogue: 4KB LDS reduce
// (overlaid on buffer 0) + s8/perm + atomicAdd (bias pre-seeded by prep).
// ---------------------------------------------------------------------------
__global__ __launch_bounds__(256)
void qgemv_kernel(const short* __restrict__ xf,
                  const int*   __restrict__ w4,
                  const float* __restrict__ s4,
                  const int*   __restrict__ w8,
                  const float* __restrict__ s8,
                  const int*   __restrict__ fwd,
                  float* __restrict__ out) {
    __shared__ __align__(16) char ldsbuf[2 * 16 * ROWB];   // 33,280 B

    const int t     = threadIdx.x;
    const int lane  = t & 63;
    const int w     = t >> 6;              // wave 0..3
    const int tile  = blockIdx.x >> 1;
    const int split = blockIdx.x & 1;
    const int nb    = tile * 16;           // tile base row
    const int i     = lane & 15;
    const int q     = lane >> 4;
    const bool is4  = (nb < N4);

    const int kbase = split * KS;          // int offset within each row

    // 4 staged rows per wave (row-major global, pre-offset by kbase)
    const int r0 = w * 4;
    const int* rowp0; const int* rowp1; const int* rowp2; const int* rowp3;
    {
        const int rg = nb + r0;
        const int* b0 = is4 ? (w4 + (size_t)rg * K)
                            : (w8 + (size_t)(rg - N4) * K);
        rowp0 = b0 + kbase;
        rowp1 = b0 + (size_t)K + kbase;
        rowp2 = b0 + (size_t)2 * K + kbase;
        rowp3 = b0 + (size_t)3 * K + kbase;
    }

    // x fragments: chunk index cg = split*128 + tt*8 + c_loc
    const short* xbase = xf + (size_t)(split * 128) * 512 + lane * 8;
    // per-row group scales: group g = split*32 + tt*2 + (w>>1)
    const float* sp = is4 ? (s4 + (size_t)(nb + i) * NG + split * 32 + (w >> 1))
                          : nullptr;

    const int c0 = w * 2;                  // this wave's 2 chunks per step
    floatx4 acc = {0.f, 0.f, 0.f, 0.f};

    auto STAGE = [&](int tt, int b) {
        char* lb = ldsbuf + b * (16 * ROWB) + r0 * ROWB;
        const int ko = tt * KT + lane * 4;          // lane*16 bytes
        gload_lds16(rowp0 + ko, lb);
        gload_lds16(rowp1 + ko, lb + ROWB);
        gload_lds16(rowp2 + ko, lb + 2 * ROWB);
        gload_lds16(rowp3 + ko, lb + 3 * ROWB);
    };

    STAGE(0, 0);

    #pragma unroll 1
    for (int tt = 0; tt < NSTEP; ++tt) {
        const int b = tt & 1;
        // x fragments + scale for THIS step, issued before next stage so the
        // counted vmcnt drains them together with stage(tt).
        const short8 xa = *(const short8*)(xbase + (size_t)(tt * 8 + c0) * 512);
        const short8 xb = *(const short8*)(xbase + (size_t)(tt * 8 + c0 + 1) * 512);
        float sv = 0.f;
        if (is4) sv = sp[tt * 2];
        __builtin_amdgcn_sched_barrier(0);   // pin x/s loads above the stage
        if (tt + 1 < NSTEP) STAGE(tt + 1, b ^ 1);
        __builtin_amdgcn_sched_barrier(0);
        // steady state outstanding: stage(tt)=4 (oldest) + x2 + s1 + stage(tt+1)=4.
        // vmcnt(4) completes everything except stage(tt+1) -> stays in flight
        // across the barrier (T4). Last iter: drain all.
        if (tt + 1 < NSTEP) asm volatile("s_waitcnt vmcnt(4)" ::: "memory");
        else                asm volatile("s_waitcnt vmcnt(0)" ::: "memory");
        __builtin_amdgcn_sched_barrier(0);
        __builtin_amdgcn_s_barrier();        // buf[b] complete for all waves

        const float sc = is4 ? sv : 1.f;
        const float sb = is4 ? -8.f * sv : -128.f;
        const char* lrow = ldsbuf + b * (16 * ROWB) + i * ROWB + q * 32;
        #pragma unroll
        for (int c2 = 0; c2 < 2; ++c2) {
            const char* lb2 = lrow + (c0 + c2) * 128;
            const int4 wa = *(const int4*)lb2;
            const int4 wz = *(const int4*)(lb2 + 16);
            short8 bf;
            bf[0] = f2bf((float)wa.x * sc + sb);
            bf[1] = f2bf((float)wa.y * sc + sb);
            bf[2] = f2bf((float)wa.z * sc + sb);
            bf[3] = f2bf((float)wa.w * sc + sb);
            bf[4] = f2bf((float)wz.x * sc + sb);
            bf[5] = f2bf((float)wz.y * sc + sb);
            bf[6] = f2bf((float)wz.z * sc + sb);
            bf[7] = f2bf((float)wz.w * sc + sb);
            acc = __builtin_amdgcn_mfma_f32_16x16x32_bf16(c2 ? xb : xa, bf, acc,
                                                          0, 0, 0);
        }
        __builtin_amdgcn_sched_barrier(0);
        __builtin_amdgcn_s_barrier();        // all reads of buf[b] done before
    }                                        // it is restaged next iter

    // ---- cross-wave reduce (LDS overlaid on buffer 0) + writeout ----
    float* red = (float*)ldsbuf;
    #pragma unroll
    for (int r = 0; r < 4; ++r)
        red[w * 256 + (q * 4 + r) * 16 + i] = acc[r];
    __syncthreads();

    {
        const int m  = t >> 4;     // 0..15 (batch row)
        const int i2 = t & 15;     // 0..15 (tile col)
        const float v = red[0 * 256 + t] + red[1 * 256 + t]
                      + red[2 * 256 + t] + red[3 * 256 + t];
        const int n  = nb + i2;
        const float scd = is4 ? 1.f : s8[n - N4];
        const int d  = fwd[n];
        atomicAdd(&out[(size_t)m * NT + d], v * scd);
    }
}

// ---------------------------------------------------------------------------
extern "C" void kernel_launch(void* const* d_in, const int* in_sizes, int n_in,
                              void* d_out, int out_size, void* d_ws, size_t ws_size,
                              hipStream_t stream) {
    const float* x        = (const float*)d_in[0];
    const int*   w_int4   = (const int*)  d_in[1];
    const float* s_int4   = (const float*)d_in[2];
    const int*   w_uint8  = (const int*)  d_in[3];
    const float* s_int8   = (const float*)d_in[4];
    const float* awq      = (const float*)d_in[5];
    const float* bias     = (const float*)d_in[6];
    const int*   inv_perm = (const int*)  d_in[7];
    // d_in[8] = group_size (==128), compile-time constant here

    short* x2bf = (short*)d_ws;                                       // 256 KB
    int*   fwd  = (int*)((char*)d_ws + (size_t)16 * K * sizeof(short)); // 32 KB

    prep_kernel<<<(16 * K) / 256, 256, 0, stream>>>(x, awq, inv_perm, bias,
                                                    x2bf, fwd, (float*)d_out);
    qgemv_kernel<<<(NT / 16) * 2, 256, 0, stream>>>(x2bf, w_int4, s_int4,
                                                    w_uint8, s_int8, fwd,
                                                    (float*)d_out);
}